// Round 17
// baseline (250.730 us; speedup 1.0000x reference)
//
#include <hip/hip_runtime.h>
#include <stdint.h>

// GumbelVQ forward, MI355X — round 17: lane=row / wave-uniform-k argmax.
// R16 control passed (env healthy; R13-15 crashes were infra). Theory: R16's
// thread-per-k layout costs 32 cache lines per load inst (64 line-req per
// wave-k-step) + per-thread z spill (VGPR=20, WRITE 2.4MB). Here lane=row:
// proj_w loads are same-address broadcasts (1 line), z lives in 8 VGPRs.
//
// Structure (all constructs from previously-passing rounds):
//  argmax : 512 blk (128 rowgroups x 4 k-slices) x 1024 thr (16 waves);
//           wave covers 128 k, ILP-2 chains (k, k+64); LDS combine ->
//           partials v f32 @ out[0,32768), idx i32 @ int-slots [32768,65536)
//  combine: 32x256, first-max over 4 slices -> indices @ out[65536,73728);
//           zeroes commit accum out[73728]
//  gather : 32x256, z_q = emb[idx] -> out[0,65536) (partials consumed);
//           commit partial via f32 atomicAdd
//  stats  : 1x1024, histogram/entropy/usage; finalize commit
// Inputs (f32): z_e (8,8,32,32), embedding (8192,8), proj_w (8192,8).

#define NCODES 8192
#define NROWS  8192

// Threefry-2x32, 20 rounds, key (0,42); x1 arrives pre-keyed (j+42), x0=0.
// Returns w0^w1 (JAX partitionable fold). Bit-exact per R10-R12/R16 passes.
__device__ __forceinline__ uint32_t gvq17_bits(uint32_t x1) {
    const uint32_t ks0 = 0u, ks1 = 42u, ks2 = 42u ^ 0x1BD11BDAu;
    uint32_t x0 = 0u;
#define TFR(r) { x0 += x1; x1 = (x1 << r) | (x1 >> (32u - r)); x1 ^= x0; }
    TFR(13u) TFR(15u) TFR(26u) TFR(6u)   x0 += ks1; x1 += ks2 + 1u;
    TFR(17u) TFR(29u) TFR(16u) TFR(24u)  x0 += ks2; x1 += ks0 + 2u;
    TFR(13u) TFR(15u) TFR(26u) TFR(6u)   x0 += ks0; x1 += ks1 + 3u;
    TFR(17u) TFR(29u) TFR(16u) TFR(24u)  x0 += ks1; x1 += ks2 + 4u;
    TFR(13u) TFR(15u) TFR(26u) TFR(6u)   x0 += ks2; x1 += ks0 + 5u;
#undef TFR
    return x0 ^ x1;
}

// gumbel = -ln(-ln u) = C - ln2*log2(-log2 u), C = -ln2*log2(ln2).
// u==0 -> -inf (can never win; ref's clamped -3.83 can't win either).
// Validated bit-identical result in R16.
#define GVQ_C   0.36651292058166435f
#define GVQ_LN2 0.69314718055994530942f
__device__ __forceinline__ float gvq17_gumbel(uint32_t bits) {
    float u = __uint_as_float((bits >> 9) | 0x3f800000u) - 1.0f;
    float l1 = __builtin_amdgcn_logf(u);            // log2(u) <= 0
    float l2 = __builtin_amdgcn_logf(0.0f - l1);    // log2(-log2 u)
    return fmaf(-GVQ_LN2, l2, GVQ_C);
}

// Phase 1: lane=row, wave-uniform k. Block=(g,s); wave wv covers
// k in [s*2048 + wv*128, +128) as two ILP chains (kk, kk+64).
__global__ __launch_bounds__(1024) void gvq17_argmax(const float* __restrict__ z_e,
                                                     const float* __restrict__ proj_w,
                                                     float* __restrict__ out) {
    __shared__ float lv[16][64];
    __shared__ int   li[16][64];
    const int tid  = threadIdx.x;
    const int lane = tid & 63;
    const int wv   = tid >> 6;                  // 0..15
    const int g    = blockIdx.x & 127;          // rowgroup
    const int s    = blockIdx.x >> 7;           // slice 0..3
    const int n    = g * 64 + lane;             // this lane's row
    const int b    = n >> 10, r = n & 1023;

    float z[8];
#pragma unroll
    for (int d = 0; d < 8; ++d)
        z[d] = z_e[b * 8192 + d * 1024 + r];    // coalesced across lanes

    const int k0 = s * 2048 + wv * 128;
    const float4* wp = (const float4*)proj_w + (k0 << 1);   // 2 float4 per row
    const uint32_t jb = (uint32_t)n * 8192u + (uint32_t)k0 + 42u;

    float bestA = -INFINITY, bestB = -INFINITY;
    int   biA = 0, biB = 0;

#pragma unroll 2
    for (int kk = 0; kk < 64; ++kk) {
        // chain A: k = k0+kk ; chain B: k = k0+64+kk (independent threefry)
        float4 a0 = wp[2 * kk];                 // same addr across wave:
        float4 a1 = wp[2 * kk + 1];             // 1-line broadcast loads
        float4 b0 = wp[2 * (kk + 64)];
        float4 b1 = wp[2 * (kk + 64) + 1];

        float dA = 0.0f, dB = 0.0f;
        dA = fmaf(z[0], a0.x, dA); dB = fmaf(z[0], b0.x, dB);
        dA = fmaf(z[1], a0.y, dA); dB = fmaf(z[1], b0.y, dB);
        dA = fmaf(z[2], a0.z, dA); dB = fmaf(z[2], b0.z, dB);
        dA = fmaf(z[3], a0.w, dA); dB = fmaf(z[3], b0.w, dB);
        dA = fmaf(z[4], a1.x, dA); dB = fmaf(z[4], b1.x, dB);
        dA = fmaf(z[5], a1.y, dA); dB = fmaf(z[5], b1.y, dB);
        dA = fmaf(z[6], a1.z, dA); dB = fmaf(z[6], b1.z, dB);
        dA = fmaf(z[7], a1.w, dA); dB = fmaf(z[7], b1.w, dB);

        float vA = dA + gvq17_gumbel(gvq17_bits(jb + (uint32_t)kk));
        float vB = dB + gvq17_gumbel(gvq17_bits(jb + (uint32_t)(kk + 64)));
        if (vA > bestA) { bestA = vA; biA = kk; }        // strict >: first max
        if (vB > bestB) { bestB = vB; biB = kk + 64; }
    }

    // merge chains: A's k always lower -> strict > for B keeps first-max.
    float best = bestA; int bi = biA;
    if (bestB > best) { best = bestB; bi = biB; }

    lv[wv][lane] = best; li[wv][lane] = k0 + bi;
    __syncthreads();
    if (tid < 64) {                              // wv ascending = k ascending
        float v = lv[0][tid]; int i = li[0][tid];
#pragma unroll
        for (int w = 1; w < 16; ++w) {
            float vw = lv[w][tid]; int iw = li[w][tid];
            if (vw > v || (vw == v && iw < i)) { v = vw; i = iw; }
        }
        const int row = g * 64 + tid;
        out[s * 8192 + row] = v;                           // v partial
        ((int*)out)[32768 + s * 8192 + row] = i;           // idx partial
    }
}

// Phase 2: exact first-max over the 4 slices -> indices; zero commit accum.
__global__ __launch_bounds__(256) void gvq17_combine(float* __restrict__ out) {
    const int n = blockIdx.x * 256 + threadIdx.x;          // grid 32
    float v = out[n];
    int   i = ((const int*)out)[32768 + n];
#pragma unroll
    for (int s = 1; s < 4; ++s) {                          // s ascending = k asc
        float vs = out[s * 8192 + n];
        int   is = ((const int*)out)[32768 + s * 8192 + n];
        if (vs > v || (vs == v && is < i)) { v = vs; i = is; }
    }
    out[65536 + n] = (float)i;
    if (n == 0) out[73728] = 0.0f;                         // commit accum
}

// Phase 3: z_q = emb[idx] (overwrites partials — consumed) + commit partial.
__global__ __launch_bounds__(256) void gvq17_gather(const float* __restrict__ z_e,
                                                    const float* __restrict__ emb,
                                                    float* __restrict__ out) {
    __shared__ float red[256];
    const int tid = threadIdx.x;
    const int n = blockIdx.x * 256 + tid;                  // grid 32
    const int idx = (int)out[65536 + n] & 8191;
    const int b = n >> 10, r = n & 1023;

    const float4* ep = (const float4*)(emb + idx * 8);
    float4 ea = ep[0], eb = ep[1];
    float e[8] = {ea.x, ea.y, ea.z, ea.w, eb.x, eb.y, eb.z, eb.w};

    float sq = 0.0f;
#pragma unroll
    for (int d = 0; d < 8; ++d) {
        const int pos = b * 8192 + d * 1024 + r;
        float diff = z_e[pos] - e[d];
        sq = fmaf(diff, diff, sq);
        out[pos] = e[d];                                   // z_q (B,D,H,W)
    }
    red[tid] = sq;
    __syncthreads();
    for (int t = 128; t > 0; t >>= 1) {
        if (tid < t) red[tid] += red[tid + t];
        __syncthreads();
    }
    if (tid == 0) atomicAdd(out + 73728, red[0]);
}

// Phase 4: single block: histogram -> entropy/usage; finalize commit.
__global__ __launch_bounds__(1024) void gvq17_stats(float* __restrict__ out) {
    __shared__ int counts[NCODES];                         // 32 KiB
    __shared__ float hred[1024];
    __shared__ int ired[1024];
    const int tid = threadIdx.x;

    for (int k = tid; k < NCODES; k += 1024) counts[k] = 0;
    __syncthreads();
    for (int n = tid; n < NROWS; n += 1024)
        atomicAdd(&counts[(int)out[65536 + n] & 8191], 1);
    __syncthreads();

    float h = 0.0f; int used = 0;
    for (int k = tid; k < NCODES; k += 1024) {
        int c = counts[k];
        float avg = (float)c * (1.0f / 8192.0f);
        h += avg * logf(avg + 1e-10f);                     // accurate, 8 iters
        used += (c > 0) ? 1 : 0;
    }
    hred[tid] = h; ired[tid] = used;
    __syncthreads();
    for (int t = 512; t > 0; t >>= 1) {
        if (tid < t) { hred[tid] += hred[tid + t]; ired[tid] += ired[tid + t]; }
        __syncthreads();
    }
    if (tid == 0) {
        out[73728] = 0.25f * out[73728] * (1.0f / 65536.0f);  // commit
        out[73729] = expf(-hred[0]);                          // perplexity
        out[73730] = (float)ired[0] * (1.0f / 8192.0f);       // usage
    }
}

extern "C" void kernel_launch(void* const* d_in, const int* in_sizes, int n_in,
                              void* d_out, int out_size, void* d_ws, size_t ws_size,
                              hipStream_t stream) {
    const float* z_e   = (const float*)d_in[0];
    const float* emb   = (const float*)d_in[1];
    const float* projw = (const float*)d_in[2];
    float* out = (float*)d_out;

    gvq17_argmax <<<512, 1024, 0, stream>>>(z_e, projw, out);
    gvq17_combine<<<32,  256,  0, stream>>>(out);
    gvq17_gather <<<32,  256,  0, stream>>>(z_e, emb, out);
    gvq17_stats  <<<1,   1024, 0, stream>>>(out);
}